// Round 1
// 677.343 us; speedup vs baseline: 1.0297x; 1.0297x over previous
//
#include <hip/hip_runtime.h>

typedef __attribute__((ext_vector_type(8))) short short8;
typedef __attribute__((ext_vector_type(4))) float floatx4;

#define N_PF 60000
#define N_GW 300000
#define N_SW 60000
#define EPT 1000000          // edges per (non-self) edge type
#define TOTE 7000000
#define L_CNT 1140000        // concat of 7 per-dst count arrays
#define SPAN 4096            // concat indices per radix bucket
#define N_B 279              // ceil(L_CNT / SPAN)
#define CHSZ 4096            // edges per partition chunk
#define NCH 1709             // ceil(TOTE / CHSZ)

__device__ __forceinline__ unsigned short f2bf(float f) {
  unsigned u = __float_as_uint(f);
  u = (u + 0x7FFF + ((u >> 16) & 1)) >> 16;
  return (unsigned short)u;
}
__device__ __forceinline__ float bf2f(unsigned short u) {
  return __uint_as_float((unsigned)u << 16);
}
__device__ __forceinline__ void acc8(float* a, short8 v) {
#pragma unroll
  for (int k = 0; k < 8; ++k) a[k] += bf2f((unsigned short)v[k]);
}

__device__ __forceinline__ int cnt_base(int et) {
  switch (et) {
    case 0: return 0;
    case 1: return 300000;
    case 2: return 360000;
    case 3: return 420000;
    case 4: return 480000;
    case 5: return 780000;
    default: return 840000;
  }
}

__device__ __forceinline__ const int* pick(const int* e0, const int* e1,
                                           const int* e2, const int* e3,
                                           const int* e4, const int* e5,
                                           const int* e6, int et) {
  switch (et) {
    case 0: return e0; case 1: return e1; case 2: return e2; case 3: return e3;
    case 4: return e4; case 5: return e5; default: return e6;
  }
}

// ---------------- input cast f32 -> bf16 ----------------
__global__ __launch_bounds__(256) void k_cast(const float4* __restrict__ x,
                                              ushort4* __restrict__ xb, int n4) {
  int i = blockIdx.x * 256 + threadIdx.x;
  if (i < n4) {
    float4 v = x[i];
    ushort4 o;
    o.x = f2bf(v.x); o.y = f2bf(v.y); o.z = f2bf(v.z); o.w = f2bf(v.w);
    xb[i] = o;
  }
}

// ============ CSR build via two-level radix partition (4B part entries) ====

__global__ __launch_bounds__(256) void k_h1(
    const int* e0, const int* e1, const int* e2, const int* e3,
    const int* e4, const int* e5, const int* e6, int* __restrict__ hcnt) {
  __shared__ int hist[N_B];
  int ch = blockIdx.x, t = threadIdx.x;
  for (int i = t; i < N_B; i += 256) hist[i] = 0;
  __syncthreads();
  int base = ch * CHSZ;
  int nn = TOTE - base; if (nn > CHSZ) nn = CHSZ;
#pragma unroll
  for (int u = 0; u < CHSZ / 256; ++u) {
    int o = u * 256 + t;
    if (o < nn) {
      int gid = base + o;
      int et = gid / EPT, i2 = gid - et * EPT;
      const int* ei = pick(e0, e1, e2, e3, e4, e5, e6, et);
      int idx = cnt_base(et) + ei[EPT + i2];
      atomicAdd(&hist[idx >> 12], 1);
    }
  }
  __syncthreads();
  for (int b = t; b < N_B; b += 256) hcnt[(size_t)b * NCH + ch] = hist[b];
}

__global__ __launch_bounds__(256) void k_h2a(const int* __restrict__ hcnt,
                                             int* __restrict__ btot) {
  __shared__ int sh[4];
  int b = blockIdx.x;
  const int* c = hcnt + (size_t)b * NCH;
  int s = 0;
  for (int k = threadIdx.x; k < NCH; k += 256) s += c[k];
  for (int off = 1; off < 64; off <<= 1) s += __shfl_xor(s, off, 64);
  int lane = threadIdx.x & 63, w = threadIdx.x >> 6;
  if (lane == 0) sh[w] = s;
  __syncthreads();
  if (threadIdx.x == 0) btot[b] = sh[0] + sh[1] + sh[2] + sh[3];
}

__global__ __launch_bounds__(64) void k_h2b(const int* __restrict__ btot,
                                            int* __restrict__ bbase,
                                            int* __restrict__ Sarr) {
  int lane = threadIdx.x;
  int v[5]; int s = 0;
#pragma unroll
  for (int k = 0; k < 5; ++k) {
    int i = lane * 5 + k;
    v[k] = (i < N_B) ? btot[i] : 0;
    s += v[k];
  }
  int x = s;
  for (int off = 1; off < 64; off <<= 1) {
    int tv = __shfl_up(x, off, 64);
    if (lane >= off) x += tv;
  }
  int run = x - s;
#pragma unroll
  for (int k = 0; k < 5; ++k) {
    int i = lane * 5 + k;
    if (i < N_B) bbase[i] = run;
    run += v[k];
  }
  if (lane == 63) { bbase[N_B] = x; Sarr[L_CNT] = TOTE; }
}

__global__ __launch_bounds__(256) void k_h2c(int* __restrict__ hcnt,
                                             const int* __restrict__ bbase) {
  __shared__ int sc[256];
  int b = blockIdx.x, t = threadIdx.x;
  int* c = hcnt + (size_t)b * NCH;
  int v[7]; int s = 0;
#pragma unroll
  for (int k = 0; k < 7; ++k) {
    int i = t * 7 + k;
    v[k] = (i < NCH) ? c[i] : 0;
    s += v[k];
  }
  sc[t] = s;
  __syncthreads();
  for (int off = 1; off < 256; off <<= 1) {
    int tv = (t >= off) ? sc[t - off] : 0;
    __syncthreads();
    sc[t] += tv;
    __syncthreads();
  }
  int run = bbase[b] + sc[t] - s;
#pragma unroll
  for (int k = 0; k < 7; ++k) {
    int i = t * 7 + k;
    if (i < NCH) { int vv = v[k]; c[i] = run; run += vv; }
  }
}

__global__ __launch_bounds__(256) void k_bfill(
    const int* e0, const int* e1, const int* e2, const int* e3,
    const int* e4, const int* e5, const int* e6,
    const int* __restrict__ hcnt, unsigned* __restrict__ part) {
  __shared__ int hist[N_B];
  __shared__ int segs[N_B];
  __shared__ int curb[N_B];
  __shared__ int gbase[N_B];
  __shared__ int sc[256];
  __shared__ unsigned long long stg[CHSZ];
  int ch = blockIdx.x, t = threadIdx.x;
  for (int i = t; i < N_B; i += 256) hist[i] = 0;
  __syncthreads();
  int base = ch * CHSZ;
  int nn = TOTE - base; if (nn > CHSZ) nn = CHSZ;
#pragma unroll
  for (int u = 0; u < CHSZ / 256; ++u) {
    int o = u * 256 + t;
    if (o < nn) {
      int gid = base + o;
      int et = gid / EPT, i2 = gid - et * EPT;
      const int* ei = pick(e0, e1, e2, e3, e4, e5, e6, et);
      int idx = cnt_base(et) + ei[EPT + i2];
      atomicAdd(&hist[idx >> 12], 1);
    }
  }
  __syncthreads();
  int v0 = (2 * t < N_B) ? hist[2 * t] : 0;
  int v1 = (2 * t + 1 < N_B) ? hist[2 * t + 1] : 0;
  int s = v0 + v1;
  sc[t] = s;
  __syncthreads();
  for (int off = 1; off < 256; off <<= 1) {
    int tv = (t >= off) ? sc[t - off] : 0;
    __syncthreads();
    sc[t] += tv;
    __syncthreads();
  }
  int excl = sc[t] - s;
  if (2 * t < N_B) { segs[2 * t] = excl; curb[2 * t] = excl; }
  if (2 * t + 1 < N_B) { segs[2 * t + 1] = excl + v0; curb[2 * t + 1] = excl + v0; }
  for (int b = t; b < N_B; b += 256) gbase[b] = hcnt[(size_t)b * NCH + ch];
  __syncthreads();
#pragma unroll
  for (int u = 0; u < CHSZ / 256; ++u) {
    int o = u * 256 + t;
    if (o < nn) {
      int gid = base + o;
      int et = gid / EPT, i2 = gid - et * EPT;
      const int* ei = pick(e0, e1, e2, e3, e4, e5, e6, et);
      int dst = ei[EPT + i2];
      int src = ei[i2];
      int idx = cnt_base(et) + dst;
      unsigned long long p = ((unsigned long long)idx << 32) | (unsigned)src;
      int r = atomicAdd(&curb[idx >> 12], 1);
      stg[r] = p;
    }
  }
  __syncthreads();
  for (int sdx = t; sdx < nn; sdx += 256) {
    unsigned long long p = stg[sdx];
    int idx = (int)(p >> 32);
    int b = idx >> 12;
    unsigned ent = ((unsigned)(idx & 4095) << 19) | (unsigned)(p & 0x7FFFF);
    part[(size_t)gbase[b] + (sdx - segs[b])] = ent;
  }
}

__global__ __launch_bounds__(1024) void k_cfill(
    const unsigned* __restrict__ part, const int* __restrict__ bbase,
    int* __restrict__ Sarr, int* __restrict__ col) {
  __shared__ int hist[SPAN];
  __shared__ int wt[16];
  int t = threadIdx.x;
  int lane = t & 63, wv = t >> 6;
  int b = blockIdx.x;
  int lo = b * SPAN;
  int span_n = L_CNT - lo; if (span_n > SPAN) span_n = SPAN;
  int s0 = bbase[b], s1 = bbase[b + 1];
  ((int4*)hist)[t] = (int4){0, 0, 0, 0};
  __syncthreads();
  for (int j = s0 + t; j < s1; j += 1024) {
    int local = (int)(part[j] >> 19);
    atomicAdd(&hist[local], 1);
  }
  __syncthreads();
  int4 v = ((int4*)hist)[t];
  int s = v.x + v.y + v.z + v.w;
  int x = s;
#pragma unroll
  for (int off = 1; off < 64; off <<= 1) {
    int tv = __shfl_up(x, off, 64);
    if (lane >= off) x += tv;
  }
  if (lane == 63) wt[wv] = x;
  __syncthreads();
  int woff = 0;
#pragma unroll
  for (int k = 0; k < 16; ++k) woff += (k < wv) ? wt[k] : 0;
  int run = woff + x - s;
  int4 cur4, sa4;
  cur4.x = run; sa4.x = s0 + run; run += v.x;
  cur4.y = run; sa4.y = s0 + run; run += v.y;
  cur4.z = run; sa4.z = s0 + run; run += v.z;
  cur4.w = run; sa4.w = s0 + run; run += v.w;
  __syncthreads();
  ((int4*)hist)[t] = cur4;
  if (t * 4 + 3 < span_n) {
    *(int4*)(&Sarr[lo + t * 4]) = sa4;
  } else {
    if (t * 4 + 0 < span_n) Sarr[lo + t * 4 + 0] = sa4.x;
    if (t * 4 + 1 < span_n) Sarr[lo + t * 4 + 1] = sa4.y;
    if (t * 4 + 2 < span_n) Sarr[lo + t * 4 + 2] = sa4.z;
  }
  __syncthreads();
  for (int j = s0 + t; j < s1; j += 1024) {
    unsigned p = part[j];
    int local = (int)(p >> 19);
    int r = atomicAdd(&hist[local], 1);
    col[s0 + r] = (int)(p & 0x7FFFF);
  }
}

// ---------------- weight prep (fold + swizzle -> bf16) ----------------
template <int KIN, int NE>
__global__ __launch_bounds__(256) void k_prep(
    const float* __restrict__ Wl, const float* __restrict__ Wr,
    const float* __restrict__ bl, int e0, int e1, int e2, int es,
    unsigned short* __restrict__ wsw, float* __restrict__ bias) {
  constexpr int KCAT = (NE + 1) * KIN;
  int idx = blockIdx.x * 256 + threadIdx.x;
  if (idx < KCAT * 64) {
    int j = idx & 7, lane = (idx >> 3) & 63, t = idx >> 9;
    int ct = t & 3, kc = t >> 2;
    int k = kc * 32 + ((lane >> 4) << 3) + j;
    int c = ct * 16 + (lane & 15);
    int seg = k / KIN, kk = k - seg * KIN;
    float v;
    if (seg < NE) {
      int e = (seg == 0) ? e0 : (seg == 1) ? e1 : e2;
      v = Wl[((size_t)e * 64 + c) * KIN + kk];
    } else {
      v = Wl[((size_t)es * 64 + c) * KIN + kk] +
          Wr[((size_t)es * 64 + c) * KIN + kk] +
          Wr[((size_t)e0 * 64 + c) * KIN + kk] +
          Wr[((size_t)e1 * 64 + c) * KIN + kk];
      if (NE == 3) v += Wr[((size_t)e2 * 64 + c) * KIN + kk];
    }
    wsw[idx] = f2bf(v);
  } else if (idx < KCAT * 64 + 64) {
    int c = idx - KCAT * 64;
    float v = bl[e0 * 64 + c] + bl[e1 * 64 + c] + bl[es * 64 + c];
    if (NE == 3) v += bl[e2 * 64 + c];
    bias[c] = v;
  }
}

// ------- fused 3-dst-type layer: gather(mean) + MFMA + epilogue -------
// Gather = R10's serial-chain branch-free loop (R11 lesson: lockstep chains
// regressed 2.2x -- divergent branchy bodies defeat load pipelining).
// This round: dst-row segment is no longer staged through LDS -- its MFMA
// A-fragment is loaded direct from global into registers at tile start
// (same bytes, same bf16 values). ZSTR 4*KIN+8 -> 3*KIN+8 cuts LDS so
// layer-2 goes 4 -> 6 blocks/CU and layer-1 fits 8 blocks/CU; grids resized
// to fill residency (was 1024 blocks = 4/CU for both). Segment bounds for
// all edge types are hoisted so the chain-0 startup overlaps them, and the
// e-loop is unrolled over compile-time E (constant indices, no scratch).
struct LType {
  const unsigned short* s0;
  const unsigned short* s1;
  const unsigned short* s2;
  int b0, b1, b2, ne;
  const unsigned short* xD;
  const unsigned short* wsw;
  const float* bias;
  void* hOut;
  int omode;   // 0 bf16 h, 1 f32 h, 2 fused linear+PReLU
  int ntile;   // Ndst/16
};

template <int KIN, int MINW>
__global__ __launch_bounds__(256, MINW) void k_layerF(
    const int* __restrict__ Sarr, const int* __restrict__ col, LType t0,
    LType t1, LType t2, const float* __restrict__ linW,
    const float* __restrict__ linb, const float* __restrict__ pa) {
  constexpr int ZSTR = 3 * KIN + 8;   // gathered segments only (ne<=3)
  constexpr int LPR = KIN / 8;        // lanes per feature row (8 or 4)
  constexpr int G = 64 / LPR;         // node-groups per wave (8 or 16)
  constexpr int KD = KIN / 32;        // dst-row k-chunks (1 or 2)
  __shared__ unsigned short z[4 * 16 * ZSTR];
  const int lane = threadIdx.x & 63;
  unsigned short* zw = &z[(threadIdx.x >> 6) * 16 * ZSTR];
  const int wid = (blockIdx.x * 256 + threadIdx.x) >> 6;
  const int nw = (gridDim.x * 256) >> 6;
  const int cl = lane & 15, quad = lane >> 4;
  const int g = lane / LPR;
  const int c = lane % LPR;
  const int TT = t0.ntile + t1.ntile + t2.ntile;

  for (int tile = wid; tile < TT; tile += nw) {
    LType tp;
    int lt = tile;
    if (lt < t0.ntile) tp = t0;
    else if ((lt -= t0.ntile) < t1.ntile) tp = t1;
    else { lt -= t1.ntile; tp = t2; }
    const int nb = lt * 16;
    const int ne = tp.ne;
    const int klds = ne * KD;

    // dst-row A fragments direct from global in MFMA layout; the loads
    // issue here and their latency hides under the whole gather below.
    short8 adst[KD];
#pragma unroll
    for (int kd = 0; kd < KD; ++kd)
      adst[kd] = *(const short8*)(tp.xD + (size_t)(nb + cl) * KIN +
                                  kd * 32 + quad * 8);

    // ---- gather: serial chains per (node-group, e); branch-free body ----
#pragma unroll
    for (int i0 = 0; i0 < 16; i0 += G) {
      int n = nb + i0 + g;
      unsigned short* zr = &zw[(i0 + g) * ZSTR];
      // hoist all segment bounds so they issue together
      int s0v = Sarr[tp.b0 + n], t0v = Sarr[tp.b0 + n + 1];
      int s1v = Sarr[tp.b1 + n], t1v = Sarr[tp.b1 + n + 1];
      int s2v = 0, t2v = 0;
      if (ne == 3) { s2v = Sarr[tp.b2 + n]; t2v = Sarr[tp.b2 + n + 1]; }
#pragma unroll
      for (int E = 0; E < 3; ++E) {
        if (E < ne) {
          const unsigned short* se =
              (E == 0) ? tp.s0 : (E == 1) ? tp.s1 : tp.s2;
          int s = (E == 0) ? s0v : (E == 1) ? s1v : s2v;
          int t = (E == 0) ? t0v : (E == 1) ? t1v : t2v;
          float a0[8] = {0, 0, 0, 0, 0, 0, 0, 0};
          float a1[8] = {0, 0, 0, 0, 0, 0, 0, 0};
          int j = s;
          for (; j + 1 < t; j += 2) {
            int r0 = col[j], r1 = col[j + 1];
            short8 v0 = *(const short8*)(se + (size_t)r0 * KIN + c * 8);
            short8 v1 = *(const short8*)(se + (size_t)r1 * KIN + c * 8);
            acc8(a0, v0);
            acc8(a1, v1);
          }
          if (j < t) {
            int r0 = col[j];
            short8 v0 = *(const short8*)(se + (size_t)r0 * KIN + c * 8);
            acc8(a0, v0);
          }
          int cv = t - s;
          if (cv < 1) cv = 1;
          float inv = 1.0f / (float)cv;
          short8 o;
#pragma unroll
          for (int k = 0; k < 8; ++k)
            o[k] = (short)f2bf((a0[k] + a1[k]) * inv);
          *(short8*)(&zr[E * KIN + c * 8]) = o;
        }
      }
    }
    // ---- MFMA: 16 nodes x 64 out cols, K = (ne+1)*KIN ----
    floatx4 acc[4];
#pragma unroll
    for (int ct = 0; ct < 4; ++ct) {
      float bv = tp.bias[ct * 16 + cl];
      acc[ct] = (floatx4){bv, bv, bv, bv};
    }
    for (int kc = 0; kc < klds; ++kc) {
      short8 a = *(const short8*)(&zw[cl * ZSTR + kc * 32 + quad * 8]);
#pragma unroll
      for (int ct = 0; ct < 4; ++ct) {
        short8 b =
            *(const short8*)(tp.wsw + ((size_t)(kc * 4 + ct) * 64 + lane) * 8);
        acc[ct] = __builtin_amdgcn_mfma_f32_16x16x32_bf16(a, b, acc[ct], 0, 0, 0);
      }
    }
#pragma unroll
    for (int kd = 0; kd < KD; ++kd) {
      short8 a = adst[kd];
      int kc = klds + kd;
#pragma unroll
      for (int ct = 0; ct < 4; ++ct) {
        short8 b =
            *(const short8*)(tp.wsw + ((size_t)(kc * 4 + ct) * 64 + lane) * 8);
        acc[ct] = __builtin_amdgcn_mfma_f32_16x16x32_bf16(a, b, acc[ct], 0, 0, 0);
      }
    }
    // ---- epilogue ----
    if (tp.omode == 2) {
      float p[4] = {0.f, 0.f, 0.f, 0.f};
#pragma unroll
      for (int ct = 0; ct < 4; ++ct) {
        float w = linW[ct * 16 + cl];
#pragma unroll
        for (int r = 0; r < 4; ++r) {
          float v = acc[ct][r];
          v = v > 0.f ? v : 0.f;
          p[r] += v * w;
        }
      }
#pragma unroll
      for (int off = 1; off < 16; off <<= 1) {
#pragma unroll
        for (int r = 0; r < 4; ++r) p[r] += __shfl_xor(p[r], off, 64);
      }
      if (cl == 0) {
        float lb = linb[0], al = pa[0];
        float* o = (float*)tp.hOut;
#pragma unroll
        for (int r = 0; r < 4; ++r) {
          int n = nb + quad * 4 + r;
          float v = p[r] + lb;
          o[n] = v >= 0.f ? v : al * v;
        }
      }
    } else if (tp.omode == 1) {
#pragma unroll
      for (int ct = 0; ct < 4; ++ct)
#pragma unroll
        for (int r = 0; r < 4; ++r) {
          int n = nb + quad * 4 + r;
          float v = acc[ct][r];
          ((float*)tp.hOut)[(size_t)n * 64 + ct * 16 + cl] = v > 0.f ? v : 0.f;
        }
    } else {
#pragma unroll
      for (int ct = 0; ct < 4; ++ct)
#pragma unroll
        for (int r = 0; r < 4; ++r) {
          int n = nb + quad * 4 + r;
          float v = acc[ct][r];
          ((unsigned short*)tp.hOut)[(size_t)n * 64 + ct * 16 + cl] =
              f2bf(v > 0.f ? v : 0.f);
        }
    }
  }
}

extern "C" void kernel_launch(void* const* d_in, const int* in_sizes, int n_in,
                              void* d_out, int out_size, void* d_ws,
                              size_t ws_size, hipStream_t stream) {
  const float* x_pf = (const float*)d_in[0];
  const float* x_gw = (const float*)d_in[1];
  const float* x_sw = (const float*)d_in[2];
  const float* W1l = (const float*)d_in[3];
  const float* b1l = (const float*)d_in[4];
  const float* W1r = (const float*)d_in[5];
  const float* W2l = (const float*)d_in[6];
  const float* b2l = (const float*)d_in[7];
  const float* W2r = (const float*)d_in[8];
  const float* linW = (const float*)d_in[9];
  const float* linb = (const float*)d_in[10];
  const float* pa = (const float*)d_in[11];
  const int* e0 = (const int*)d_in[12];  // pf->gw
  const int* e1 = (const int*)d_in[13];  // gw->pf
  const int* e2 = (const int*)d_in[14];  // pf->sw
  const int* e3 = (const int*)d_in[15];  // sw->pf
  const int* e4 = (const int*)d_in[16];  // sw->gw
  const int* e5 = (const int*)d_in[17];  // gw->sw
  const int* e6 = (const int*)d_in[18];  // gw->gw
  float* out = (float*)d_out;

  char* w = (char*)d_ws;
  size_t off = 0;
  auto alloc = [&](size_t bytes) -> void* {
    void* p = w + off;
    off += bytes;
    off = (off + 255) & ~(size_t)255;
    return p;
  };
  unsigned* part = (unsigned*)alloc((size_t)TOTE * 4);
  int* col = (int*)alloc((size_t)TOTE * 4);
  int* Sarr = (int*)alloc((size_t)(L_CNT + 1) * 4);
  int* hcnt = (int*)alloc((size_t)N_B * NCH * 4);
  int* btot = (int*)alloc((N_B + 1) * 4);
  int* bbase = (int*)alloc((N_B + 1) * 4);
  unsigned short* xb_pf = (unsigned short*)alloc((size_t)N_PF * 32 * 2);
  unsigned short* xb_gw = (unsigned short*)alloc((size_t)N_GW * 32 * 2);
  unsigned short* xb_sw = (unsigned short*)alloc((size_t)N_SW * 32 * 2);
  unsigned short* h1_pf = (unsigned short*)alloc((size_t)N_PF * 64 * 2);
  unsigned short* h1_gw = (unsigned short*)alloc((size_t)N_GW * 64 * 2);
  unsigned short* h1_sw = (unsigned short*)alloc((size_t)N_SW * 64 * 2);
  unsigned short* w1gw = (unsigned short*)alloc(128 * 64 * 2);
  unsigned short* w1pf = (unsigned short*)alloc(96 * 64 * 2);
  unsigned short* w1sw = (unsigned short*)alloc(96 * 64 * 2);
  unsigned short* w2gw = (unsigned short*)alloc(256 * 64 * 2);
  unsigned short* w2pf = (unsigned short*)alloc(192 * 64 * 2);
  unsigned short* w2sw = (unsigned short*)alloc(192 * 64 * 2);
  float* bs1gw = (float*)alloc(64 * 4);
  float* bs1pf = (float*)alloc(64 * 4);
  float* bs1sw = (float*)alloc(64 * 4);
  float* bs2gw = (float*)alloc(64 * 4);
  float* bs2pf = (float*)alloc(64 * 4);
  float* bs2sw = (float*)alloc(64 * 4);

  // input casts
  k_cast<<<(N_PF * 8 + 255) / 256, 256, 0, stream>>>((const float4*)x_pf,
                                                     (ushort4*)xb_pf, N_PF * 8);
  k_cast<<<(N_GW * 8 + 255) / 256, 256, 0, stream>>>((const float4*)x_gw,
                                                     (ushort4*)xb_gw, N_GW * 8);
  k_cast<<<(N_SW * 8 + 255) / 256, 256, 0, stream>>>((const float4*)x_sw,
                                                     (ushort4*)xb_sw, N_SW * 8);

  // CSR build: radix partition
  k_h1<<<NCH, 256, 0, stream>>>(e0, e1, e2, e3, e4, e5, e6, hcnt);
  k_h2a<<<N_B, 256, 0, stream>>>(hcnt, btot);
  k_h2b<<<1, 64, 0, stream>>>(btot, bbase, Sarr);
  k_h2c<<<N_B, 256, 0, stream>>>(hcnt, bbase);
  k_bfill<<<NCH, 256, 0, stream>>>(e0, e1, e2, e3, e4, e5, e6, hcnt, part);
  k_cfill<<<N_B, 1024, 0, stream>>>(part, bbase, Sarr, col);

  // weight prep
  k_prep<32, 3><<<(128 * 64 + 64 + 255) / 256, 256, 0, stream>>>(
      W1l, W1r, b1l, 0, 4, 6, 7, w1gw, bs1gw);
  k_prep<32, 2><<<(96 * 64 + 64 + 255) / 256, 256, 0, stream>>>(
      W1l, W1r, b1l, 1, 3, 0, 9, w1pf, bs1pf);
  k_prep<32, 2><<<(96 * 64 + 64 + 255) / 256, 256, 0, stream>>>(
      W1l, W1r, b1l, 2, 5, 0, 8, w1sw, bs1sw);
  k_prep<64, 3><<<(256 * 64 + 64 + 255) / 256, 256, 0, stream>>>(
      W2l, W2r, b2l, 0, 4, 6, 7, w2gw, bs2gw);
  k_prep<64, 2><<<(192 * 64 + 64 + 255) / 256, 256, 0, stream>>>(
      W2l, W2r, b2l, 1, 3, 0, 9, w2pf, bs2pf);
  k_prep<64, 2><<<(192 * 64 + 64 + 255) / 256, 256, 0, stream>>>(
      W2l, W2r, b2l, 2, 5, 0, 8, w2sw, bs2sw);

  // layer 1 (KIN=32): one fused launch for gw/pf/sw
  // LDS 13312 B/block -> 8 blocks/CU (thread-capped); grid fills residency.
  LType a0{xb_pf, xb_sw, xb_gw, 0, 480000, 840000, 3,
           xb_gw, w1gw, bs1gw, h1_gw, 0, N_GW / 16};
  LType a1{xb_gw, xb_sw, nullptr, 300000, 420000, 0, 2,
           xb_pf, w1pf, bs1pf, h1_pf, 0, N_PF / 16};
  LType a2{xb_pf, xb_gw, nullptr, 360000, 780000, 0, 2,
           xb_sw, w1sw, bs1sw, h1_sw, 0, N_SW / 16};
  k_layerF<32, 8><<<2048, 256, 0, stream>>>(Sarr, col, a0, a1, a2, linW, linb,
                                            pa);

  // layer 2 (KIN=64): one fused launch; gw/sw fuse linear+PReLU, pf -> f32
  // LDS 25600 B/block -> 6 blocks/CU (was 4); grid fills residency.
  LType c0{h1_pf, h1_sw, h1_gw, 0, 480000, 840000, 3,
           h1_gw, w2gw, bs2gw, out, 2, N_GW / 16};
  LType c1{h1_gw, h1_sw, nullptr, 300000, 420000, 0, 2,
           h1_pf, w2pf, bs2pf, out + 360000, 1, N_PF / 16};
  LType c2{h1_pf, h1_gw, nullptr, 360000, 780000, 0, 2,
           h1_sw, w2sw, bs2sw, out + N_GW, 2, N_SW / 16};
  k_layerF<64, 6><<<1536, 256, 0, stream>>>(Sarr, col, c0, c1, c2, linW, linb,
                                            pa);
}